// Round 5
// baseline (268.714 us; speedup 1.0000x reference)
//
#include <hip/hip_runtime.h>
#include <hip/hip_bf16.h>
#include <cstdint>

#define N_SRC 100000
#define N_DST 25000
#define N_EDGE 300000
// D_IN = D_HID = D_OUT = 256, concat K = 512

typedef float f32x4 __attribute__((ext_vector_type(4)));
typedef __bf16 bf16x8 __attribute__((ext_vector_type(8)));

__device__ __forceinline__ unsigned short f2bf(float f) {
    union { float f; unsigned int u; } v; v.f = f;
    unsigned int u = v.u;
    u += 0x7FFFu + ((u >> 16) & 1u);   // RNE; inputs finite
    return (unsigned short)(u >> 16);
}
__device__ __forceinline__ float bf2f(unsigned int bits16) {
    union { unsigned int u; float f; } v; v.u = bits16 << 16;
    return v.f;
}

// asm-pinned 16B loads: compiler cannot sink these past the vmcnt waits.
__device__ __forceinline__ void gload16(uint4& d, const void* p) {
    asm volatile("global_load_dwordx4 %0, %1, off" : "=v"(d) : "v"(p) : "memory");
}
__device__ __forceinline__ void gload16(float4& d, const void* p) {
    asm volatile("global_load_dwordx4 %0, %1, off" : "=v"(d) : "v"(p) : "memory");
}
template<int N> __device__ __forceinline__ void vmwait() {
    asm volatile("s_waitcnt vmcnt(%0)" :: "n"(N) : "memory");
    __builtin_amdgcn_sched_barrier(0);   // rule #18: block MFMA hoisting past wait
}

// ---- cast + transpose weights: Qt[n][k] = bf16(Q_w[k][n]), Wt[n][k] = bf16(W_w[k][n])
__global__ void cast_weights(const float* __restrict__ Qw, const float* __restrict__ Ww,
                             unsigned short* __restrict__ Qt, unsigned short* __restrict__ Wt) {
    int i = blockIdx.x * blockDim.x + threadIdx.x;
    if (i < 256 * 256) {
        int n = i >> 8, k = i & 255;
        Qt[n * 256 + k] = f2bf(Qw[k * 256 + n]);
    } else if (i < 256 * 256 + 512 * 256) {
        int j = i - 256 * 256;
        int n = j >> 9, k = j & 511;
        Wt[n * 512 + k] = f2bf(Ww[k * 256 + n]);
    }
}

// ---- CSR build
__global__ void hist_kernel(const int* __restrict__ dst_idx, int* __restrict__ counts) {
    int i = blockIdx.x * blockDim.x + threadIdx.x;
    if (i < N_EDGE) atomicAdd(&counts[dst_idx[i]], 1);
}

__global__ __launch_bounds__(1024) void scan_kernel(const int* __restrict__ counts,
                                                    int* __restrict__ offsets, int n) {
    __shared__ int wsum[16];
    const int t = threadIdx.x;
    const int wid = t >> 6, lane = t & 63;
    int carry = 0;
    if (t == 0) offsets[0] = 0;
    for (int base = 0; base < n; base += 1024) {
        int x = (base + t < n) ? counts[base + t] : 0;
        #pragma unroll
        for (int off = 1; off < 64; off <<= 1) {
            int y = __shfl_up(x, off, 64);
            if (lane >= off) x += y;
        }
        if (lane == 63) wsum[wid] = x;
        __syncthreads();
        if (t < 16) {
            int w = wsum[t];
            #pragma unroll
            for (int off = 1; off < 16; off <<= 1) {
                int y = __shfl_up(w, off, 64);
                if (t >= off) w += y;
            }
            wsum[t] = w;
        }
        __syncthreads();
        int pre = (wid > 0) ? wsum[wid - 1] : 0;
        int incl = carry + pre + x;
        if (base + t < n) offsets[base + t + 1] = incl;
        carry += wsum[15];
        __syncthreads();
    }
}

__global__ void scatter_kernel(const int* __restrict__ dst_idx, const int* __restrict__ offsets,
                               int* __restrict__ counts, int* __restrict__ edge_list) {
    int i = blockIdx.x * blockDim.x + threadIdx.x;
    if (i < N_EDGE) {
        int d = dst_idx[i];
        int pos = offsets[d] + (atomicSub(&counts[d], 1) - 1);
        edge_list[pos] = i;
    }
}

// ---- barrier-free pipelined GEMM. Wave = 32 rows x 64 cols; block = 512 thr
// = 8 waves = 2 row-groups x 4 n-tiles (block covers 64 rows x 256 cols).
// All A/B loads are asm-pinned into register rings (A 3-deep, B 2-deep) with
// hand-counted vmcnt; no __syncthreads in the K loop. NORM adds an epilogue
// LDS exchange across the 4 n-tile waves of a row-group.
template<int KDIM, bool A_F32, bool NORM>
__global__ __launch_bounds__(512, 3) void gemm_wave(
    const float* __restrict__ Af, const unsigned short* __restrict__ Ab,
    const unsigned short* __restrict__ Bt, const float* __restrict__ bias,
    unsigned short* __restrict__ Cb, float* __restrict__ Cf, int M)
{
    constexpr int NKS = KDIM / 32;        // 8 (K=256) or 16 (K=512)
    constexpr int IA  = A_F32 ? 4 : 2;    // load-instrs per A ring slot
    __shared__ float norml[2][4][32];

    const int tid = threadIdx.x;
    const int wv = tid >> 6, lane = tid & 63;
    const int rg = wv >> 2, nt = wv & 3;
    const int g = lane >> 4, cl = lane & 15;
    const int m0 = blockIdx.x * 64 + rg * 32;
    const int n0 = nt * 64;

    f32x4 acc[2][4];
    #pragma unroll
    for (int i = 0; i < 2; ++i)
        #pragma unroll
        for (int j = 0; j < 4; ++j)
            acc[i][j] = (f32x4){0.f, 0.f, 0.f, 0.f};

    const int rA0 = min(m0 + cl,      M - 1);
    const int rA1 = min(m0 + 16 + cl, M - 1);

    float4 Arf[3][2][2];   // f32 A ring  [slot][mi][half]
    uint4  Arb[3][2];      // bf16 A ring [slot][mi]
    uint4  Br[2][4];       // B ring      [slot][ni]

    auto issueA = [&](int slot, int s) {
        if constexpr (A_F32) {
            const float* p0 = Af + (size_t)rA0 * KDIM + s * 32 + g * 8;
            const float* p1 = Af + (size_t)rA1 * KDIM + s * 32 + g * 8;
            gload16(Arf[slot][0][0], p0); gload16(Arf[slot][0][1], p0 + 4);
            gload16(Arf[slot][1][0], p1); gload16(Arf[slot][1][1], p1 + 4);
        } else {
            gload16(Arb[slot][0], Ab + (size_t)rA0 * KDIM + s * 32 + g * 8);
            gload16(Arb[slot][1], Ab + (size_t)rA1 * KDIM + s * 32 + g * 8);
        }
    };
    auto issueB = [&](int slot, int s) {
        #pragma unroll
        for (int ni = 0; ni < 4; ++ni)
            gload16(Br[slot][ni],
                    Bt + (size_t)(n0 + ni * 16 + cl) * KDIM + s * 32 + g * 8);
    };
    auto compute = [&](int s) {
        bf16x8 af[2];
        if constexpr (A_F32) {
            #pragma unroll
            for (int mi = 0; mi < 2; ++mi) {
                const float4 lo = Arf[s % 3][mi][0], hi = Arf[s % 3][mi][1];
                af[mi][0] = (__bf16)lo.x; af[mi][1] = (__bf16)lo.y;
                af[mi][2] = (__bf16)lo.z; af[mi][3] = (__bf16)lo.w;
                af[mi][4] = (__bf16)hi.x; af[mi][5] = (__bf16)hi.y;
                af[mi][6] = (__bf16)hi.z; af[mi][7] = (__bf16)hi.w;
            }
        } else {
            af[0] = __builtin_bit_cast(bf16x8, Arb[s % 3][0]);
            af[1] = __builtin_bit_cast(bf16x8, Arb[s % 3][1]);
        }
        #pragma unroll
        for (int mi = 0; mi < 2; ++mi)
            #pragma unroll
            for (int ni = 0; ni < 4; ++ni)
                acc[mi][ni] = __builtin_amdgcn_mfma_f32_16x16x32_bf16(
                    af[mi], __builtin_bit_cast(bf16x8, Br[s & 1][ni]), acc[mi][ni], 0, 0, 0);
    };

    // Prologue: B0 A0 A1 B1 A2 in flight (8+3*IA instrs).
    issueB(0, 0); issueA(0, 0); issueA(1, 1); issueB(1, 1); issueA(2, 2);
    vmwait<4 + 2 * IA>();           // retire B0,A0; keep A1,B1,A2
    compute(0);
    // Steady: entering step s outstanding = A[s],B[s],A[s+1] (oldest first).
    #pragma unroll
    for (int s = 1; s <= NKS - 3; ++s) {
        issueB((s + 1) & 1, s + 1);
        issueA((s + 2) % 3, s + 2);
        vmwait<4 + 2 * IA>();       // retire A[s],B[s]
        compute(s);
    }
    issueB((NKS - 1) & 1, NKS - 1);
    vmwait<4 + IA>();               // retire A[NKS-2],B[NKS-2]
    compute(NKS - 2);
    vmwait<0>();
    compute(NKS - 1);

    float bcol[4];
    #pragma unroll
    for (int ni = 0; ni < 4; ++ni) bcol[ni] = bias[n0 + ni * 16 + cl];

    if constexpr (!NORM) {
        #pragma unroll
        for (int mi = 0; mi < 2; ++mi) {
            const int rowb = m0 + mi * 16 + g * 4;
            #pragma unroll
            for (int ni = 0; ni < 4; ++ni) {
                const int col = n0 + ni * 16 + cl;
                #pragma unroll
                for (int r = 0; r < 4; ++r) {
                    const int row = rowb + r;
                    if (row < M) {
                        float v = fmaxf(acc[mi][ni][r] + bcol[ni], 0.f);
                        Cb[(size_t)row * 256 + col] = f2bf(v);
                    }
                }
            }
        }
    } else {
        #pragma unroll
        for (int mi = 0; mi < 2; ++mi) {
            #pragma unroll
            for (int r = 0; r < 4; ++r) {
                float s = 0.f;
                #pragma unroll
                for (int ni = 0; ni < 4; ++ni) {
                    float v = fmaxf(acc[mi][ni][r] + bcol[ni], 0.f);
                    acc[mi][ni][r] = v;
                    s += v * v;
                }
                #pragma unroll
                for (int m = 1; m < 16; m <<= 1) s += __shfl_xor(s, m, 64);
                if (cl == 0) norml[rg][nt][mi * 16 + g * 4 + r] = s;
            }
        }
        __syncthreads();
        #pragma unroll
        for (int mi = 0; mi < 2; ++mi) {
            #pragma unroll
            for (int r = 0; r < 4; ++r) {
                const int rl = mi * 16 + g * 4 + r;
                const float tot = norml[rg][0][rl] + norml[rg][1][rl]
                                + norml[rg][2][rl] + norml[rg][3][rl];
                const float rn = tot > 0.f ? rsqrtf(tot) : 1.0f;
                const int row = m0 + rl;
                if (row < M) {
                    #pragma unroll
                    for (int ni = 0; ni < 4; ++ni)
                        Cf[(size_t)row * 256 + n0 + ni * 16 + cl] = acc[mi][ni][r] * rn;
                }
            }
        }
    }
}

// ---- per-dst aggregation: one wave per dst; unroll-2 on edges
__global__ __launch_bounds__(256) void aggregate_kernel(
    const unsigned short* __restrict__ nft, const float* __restrict__ h_dst,
    const float* __restrict__ weights, const int* __restrict__ src_idx,
    const int* __restrict__ edge_list, const int* __restrict__ offsets,
    unsigned short* __restrict__ xb)
{
    int d = blockIdx.x * 4 + (threadIdx.x >> 6);
    if (d >= N_DST) return;
    int lane = threadIdx.x & 63;
    int p0 = offsets[d], p1 = offsets[d + 1];
    float a0 = 0.f, a1 = 0.f, a2 = 0.f, a3 = 0.f, wsum = 0.f;
    int p = p0;
    for (; p + 1 < p1; p += 2) {
        int e0 = edge_list[p], e1 = edge_list[p + 1];
        float w0 = weights[e0], w1 = weights[e1];
        int s0 = src_idx[e0], s1 = src_idx[e1];
        uint2 v0 = *reinterpret_cast<const uint2*>(nft + (size_t)s0 * 256 + lane * 4);
        uint2 v1 = *reinterpret_cast<const uint2*>(nft + (size_t)s1 * 256 + lane * 4);
        wsum += w0 + w1;
        a0 += w0 * bf2f(v0.x & 0xffffu) + w1 * bf2f(v1.x & 0xffffu);
        a1 += w0 * bf2f(v0.x >> 16)     + w1 * bf2f(v1.x >> 16);
        a2 += w0 * bf2f(v0.y & 0xffffu) + w1 * bf2f(v1.y & 0xffffu);
        a3 += w0 * bf2f(v0.y >> 16)     + w1 * bf2f(v1.y >> 16);
    }
    if (p < p1) {
        int e = edge_list[p];
        float w = weights[e];
        int s = src_idx[e];
        wsum += w;
        uint2 v = *reinterpret_cast<const uint2*>(nft + (size_t)s * 256 + lane * 4);
        a0 += w * bf2f(v.x & 0xffffu);
        a1 += w * bf2f(v.x >> 16);
        a2 += w * bf2f(v.y & 0xffffu);
        a3 += w * bf2f(v.y >> 16);
    }
    float inv = 1.0f / fmaxf(wsum, 1.0f);
    uint2 pk;
    pk.x = (unsigned)f2bf(a0 * inv) | ((unsigned)f2bf(a1 * inv) << 16);
    pk.y = (unsigned)f2bf(a2 * inv) | ((unsigned)f2bf(a3 * inv) << 16);
    *reinterpret_cast<uint2*>(xb + (size_t)d * 512 + lane * 4) = pk;
    float4 h = *reinterpret_cast<const float4*>(h_dst + (size_t)d * 256 + lane * 4);
    uint2 q;
    q.x = (unsigned)f2bf(h.x) | ((unsigned)f2bf(h.y) << 16);
    q.y = (unsigned)f2bf(h.z) | ((unsigned)f2bf(h.w) << 16);
    *reinterpret_cast<uint2*>(xb + (size_t)d * 512 + 256 + lane * 4) = q;
}

extern "C" void kernel_launch(void* const* d_in, const int* in_sizes, int n_in,
                              void* d_out, int out_size, void* d_ws, size_t ws_size,
                              hipStream_t stream) {
    const float* h_src   = (const float*)d_in[0];
    const float* h_dst   = (const float*)d_in[1];
    const float* weights = (const float*)d_in[2];
    const float* Q_w     = (const float*)d_in[3];
    const float* Q_b     = (const float*)d_in[4];
    const float* W_w     = (const float*)d_in[5];
    const float* W_b     = (const float*)d_in[6];
    const int* src_idx   = (const int*)d_in[7];
    const int* dst_idx   = (const int*)d_in[8];
    float* out = (float*)d_out;

    char* ws = (char*)d_ws;
    unsigned short* nft = (unsigned short*)(ws);               // 51,200,000
    unsigned short* xb  = (unsigned short*)(ws + 51200000);    // 25,600,000
    unsigned short* Qt  = (unsigned short*)(ws + 76800000);    // 131,072
    unsigned short* Wt  = (unsigned short*)(ws + 76931072);    // 262,144
    int* counts    = (int*)(ws + 77193216);                    // 100,000
    int* offsets   = (int*)(ws + 77293216);                    // 100,004
    int* edge_list = (int*)(ws + 77393220);                    // 1,200,000 (~78.6 MB)

    hipMemsetAsync(counts, 0, N_DST * sizeof(int), stream);

    cast_weights<<<768, 256, 0, stream>>>(Q_w, W_w, Qt, Wt);
    hist_kernel<<<(N_EDGE + 255) / 256, 256, 0, stream>>>(dst_idx, counts);
    scan_kernel<<<1, 1024, 0, stream>>>(counts, offsets, N_DST);
    scatter_kernel<<<(N_EDGE + 255) / 256, 256, 0, stream>>>(dst_idx, offsets, counts, edge_list);

    // GEMM1: 1563 blocks x 512 thr (12504 waves), 64 rows x 256 cols per block
    gemm_wave<256, true, false><<<(N_SRC + 63) / 64, 512, 0, stream>>>(
        h_src, nullptr, Qt, Q_b, nft, nullptr, N_SRC);

    aggregate_kernel<<<N_DST / 4, 256, 0, stream>>>(
        nft, h_dst, weights, src_idx, edge_list, offsets, xb);

    // GEMM2: 391 blocks x 512 thr, row-L2-norm fused in epilogue
    gemm_wave<512, false, true><<<(N_DST + 63) / 64, 512, 0, stream>>>(
        nullptr, xb, Wt, W_b, nullptr, out, N_DST);

    (void)in_sizes; (void)n_in; (void)out_size; (void)ws_size;
}

// Round 7
// 247.559 us; speedup vs baseline: 1.0855x; 1.0855x over previous
//
#include <hip/hip_runtime.h>
#include <hip/hip_bf16.h>
#include <cstdint>

#define N_SRC 100000
#define N_DST 25000
#define N_EDGE 300000
// D_IN = D_HID = D_OUT = 256, concat K = 512

typedef float f32x4 __attribute__((ext_vector_type(4)));
typedef __bf16 bf16x8 __attribute__((ext_vector_type(8)));

__device__ __forceinline__ unsigned short f2bf(float f) {
    union { float f; unsigned int u; } v; v.f = f;
    unsigned int u = v.u;
    u += 0x7FFFu + ((u >> 16) & 1u);   // RNE; inputs finite
    return (unsigned short)(u >> 16);
}
__device__ __forceinline__ float bf2f(unsigned int bits16) {
    union { unsigned int u; float f; } v; v.u = bits16 << 16;
    return v.f;
}

// asm-pinned 16B loads (cannot be sunk/reordered vs the counted waits)
__device__ __forceinline__ void gload16(uint4& d, const void* p) {
    asm volatile("global_load_dwordx4 %0, %1, off" : "=v"(d) : "v"(p) : "memory");
}
__device__ __forceinline__ void gload16(float4& d, const void* p) {
    asm volatile("global_load_dwordx4 %0, %1, off" : "=v"(d) : "v"(p) : "memory");
}
#define VMWAIT(N) do { asm volatile("s_waitcnt vmcnt(" #N ")" ::: "memory"); \
                       __builtin_amdgcn_sched_barrier(0); } while (0)

// ---- cast + transpose weights: Qt[n][k] = bf16(Q_w[k][n]), Wt[n][k] = bf16(W_w[k][n])
__global__ void cast_weights(const float* __restrict__ Qw, const float* __restrict__ Ww,
                             unsigned short* __restrict__ Qt, unsigned short* __restrict__ Wt) {
    int i = blockIdx.x * blockDim.x + threadIdx.x;
    if (i < 256 * 256) {
        int n = i >> 8, k = i & 255;
        Qt[n * 256 + k] = f2bf(Qw[k * 256 + n]);
    } else if (i < 256 * 256 + 512 * 256) {
        int j = i - 256 * 256;
        int n = j >> 9, k = j & 511;
        Wt[n * 512 + k] = f2bf(Ww[k * 256 + n]);
    }
}

// ---- CSR build
__global__ void hist_kernel(const int* __restrict__ dst_idx, int* __restrict__ counts) {
    int i = blockIdx.x * blockDim.x + threadIdx.x;
    if (i < N_EDGE) atomicAdd(&counts[dst_idx[i]], 1);
}

__global__ __launch_bounds__(1024) void scan_kernel(const int* __restrict__ counts,
                                                    int* __restrict__ offsets, int n) {
    __shared__ int wsum[16];
    const int t = threadIdx.x;
    const int wid = t >> 6, lane = t & 63;
    int carry = 0;
    if (t == 0) offsets[0] = 0;
    for (int base = 0; base < n; base += 1024) {
        int x = (base + t < n) ? counts[base + t] : 0;
        #pragma unroll
        for (int off = 1; off < 64; off <<= 1) {
            int y = __shfl_up(x, off, 64);
            if (lane >= off) x += y;
        }
        if (lane == 63) wsum[wid] = x;
        __syncthreads();
        if (t < 16) {
            int w = wsum[t];
            #pragma unroll
            for (int off = 1; off < 16; off <<= 1) {
                int y = __shfl_up(w, off, 64);
                if (t >= off) w += y;
            }
            wsum[t] = w;
        }
        __syncthreads();
        int pre = (wid > 0) ? wsum[wid - 1] : 0;
        int incl = carry + pre + x;
        if (base + t < n) offsets[base + t + 1] = incl;
        carry += wsum[15];
        __syncthreads();
    }
}

__global__ void scatter_kernel(const int* __restrict__ dst_idx, const int* __restrict__ offsets,
                               int* __restrict__ counts, int* __restrict__ edge_list) {
    int i = blockIdx.x * blockDim.x + threadIdx.x;
    if (i < N_EDGE) {
        int d = dst_idx[i];
        int pos = offsets[d] + (atomicSub(&counts[d], 1) - 1);
        edge_list[pos] = i;
    }
}

// ---- GEMM1: nft = relu(h_src @ Qt^T + Qb), bf16 out.
// B (128KB) fully LDS-resident, XOR-swizzled 16B blocks -> conflict-free
// ds_read_b128. Grid = 256 blocks (1/CU); block owns a balanced contiguous
// range of 16-row tiles (24-25); 12 waves round-robin tiles. Wave tile =
// 16 rows x 256 cols => acc[16] (64 VGPR). A (f32, HBM) streams through a
// 5-deep asm ring, counted vmcnt; VMWAIT(0) at tile start drains stores.
__global__ __launch_bounds__(768, 3) void gemm1_lds(
    const float* __restrict__ Af, const unsigned short* __restrict__ Bt,
    const float* __restrict__ bias, unsigned short* __restrict__ Cb)
{
    __shared__ __align__(16) unsigned char Bs[131072];
    const int tid = threadIdx.x;
    #pragma unroll
    for (int i = 0; i < 11; ++i) {
        int idx = tid + i * 768;
        if (idx < 8192) {
            int n = idx >> 5, kb = idx & 31;
            uint4 v = *reinterpret_cast<const uint4*>(Bt + n * 256 + kb * 8);
            *reinterpret_cast<uint4*>(&Bs[n * 512 + ((kb ^ (n & 7)) * 16)]) = v;
        }
    }
    __syncthreads();

    const int wv = tid >> 6, lane = tid & 63, g = lane >> 4, cl = lane & 15;
    const int b = blockIdx.x;
    const int t0 = (b * 6250) >> 8;          // 6250 tiles of 16 rows, balanced
    const int t1 = ((b + 1) * 6250) >> 8;

    for (int t = t0 + wv; t < t1; t += 12) {
        VMWAIT(0);                            // exact counts: drain prior stores
        const int m0 = t * 16;
        const float* ap = Af + (size_t)(m0 + cl) * 256;

        f32x4 acc[16];
        #pragma unroll
        for (int ni = 0; ni < 16; ++ni) acc[ni] = (f32x4){0.f, 0.f, 0.f, 0.f};

        float4 Ar[5][2];
        auto issueA = [&](int slot, int s) {
            const float* p = ap + s * 32 + g * 8;
            gload16(Ar[slot][0], p);
            gload16(Ar[slot][1], p + 4);
        };
        auto computeA = [&](int slot, int s) {
            const float4 lo = Ar[slot][0], hi = Ar[slot][1];
            bf16x8 af;
            af[0] = (__bf16)lo.x; af[1] = (__bf16)lo.y; af[2] = (__bf16)lo.z; af[3] = (__bf16)lo.w;
            af[4] = (__bf16)hi.x; af[5] = (__bf16)hi.y; af[6] = (__bf16)hi.z; af[7] = (__bf16)hi.w;
            #pragma unroll
            for (int ni = 0; ni < 16; ++ni) {
                const bf16x8 bf = *reinterpret_cast<const bf16x8*>(
                    &Bs[(ni * 16 + cl) * 512 + (((s * 4 + g) ^ (cl & 7)) * 16)]);
                acc[ni] = __builtin_amdgcn_mfma_f32_16x16x32_bf16(af, bf, acc[ni], 0, 0, 0);
            }
        };

        issueA(0, 0); issueA(1, 1); issueA(2, 2); issueA(3, 3); issueA(4, 4);
        VMWAIT(8); computeA(0, 0); issueA(0, 5);
        VMWAIT(8); computeA(1, 1); issueA(1, 6);
        VMWAIT(8); computeA(2, 2); issueA(2, 7);
        VMWAIT(8); computeA(3, 3);
        VMWAIT(6); computeA(4, 4);
        VMWAIT(4); computeA(0, 5);
        VMWAIT(2); computeA(1, 6);
        VMWAIT(0); computeA(2, 7);

        #pragma unroll
        for (int r = 0; r < 4; ++r) {
            const int row = m0 + g * 4 + r;
            #pragma unroll
            for (int ni = 0; ni < 16; ++ni) {
                float v = fmaxf(acc[ni][r] + bias[ni * 16 + cl], 0.f);
                Cb[(size_t)row * 256 + ni * 16 + cl] = f2bf(v);
            }
        }
    }
}

// ---- GEMM2: out = rownorm(relu(xb @ Wt^T + Wb)), f32 out.
// Wave = 16 rows x 128-col panel (acc[8]); block = 256 thr = 2 row-tiles x
// 2 panels. A+B stream from L2 via joint 3-deep asm ring (9 loads/slot),
// counted VMWAIT(9). Norm: 256B-LDS ssq exchange between the 2 panel waves.
__global__ __launch_bounds__(256, 3) void gemm2_l2(
    const unsigned short* __restrict__ Ab, const unsigned short* __restrict__ Bt,
    const float* __restrict__ bias, float* __restrict__ Cf, int M)
{
    __shared__ float ssq_s[2][2][16];
    const int tid = threadIdx.x;
    const int wv = tid >> 6, lane = tid & 63, g = lane >> 4, cl = lane & 15;
    const int rt = wv >> 1, pn = wv & 1;
    const int m0 = blockIdx.x * 32 + rt * 16;
    const int r0 = min(m0 + cl, M - 1);
    const unsigned short* ap = Ab + (size_t)r0 * 512;
    const unsigned short* bp = Bt + (size_t)(pn * 128 + cl) * 512;

    f32x4 acc[8];
    #pragma unroll
    for (int ni = 0; ni < 8; ++ni) acc[ni] = (f32x4){0.f, 0.f, 0.f, 0.f};

    uint4 Br[3][8];
    uint4 Aru[3];
    auto issueBoth = [&](int slot, int s) {
        #pragma unroll
        for (int ni = 0; ni < 8; ++ni)
            gload16(Br[slot][ni], bp + (size_t)ni * 8192 + s * 32 + g * 8);
        gload16(Aru[slot], ap + s * 32 + g * 8);
    };
    auto computeB = [&](int slot) {
        const bf16x8 af = __builtin_bit_cast(bf16x8, Aru[slot]);
        #pragma unroll
        for (int ni = 0; ni < 8; ++ni)
            acc[ni] = __builtin_amdgcn_mfma_f32_16x16x32_bf16(
                af, __builtin_bit_cast(bf16x8, Br[slot][ni]), acc[ni], 0, 0, 0);
    };

    issueBoth(0, 0); issueBoth(1, 1);
    #pragma unroll
    for (int s = 0; s < 14; ++s) {
        VMWAIT(9);
        issueBoth((s + 2) % 3, s + 2);
        computeB(s % 3);
    }
    VMWAIT(9); computeB(2);     // s=14
    VMWAIT(0); computeB(0);     // s=15

    float bcol[8];
    #pragma unroll
    for (int ni = 0; ni < 8; ++ni) bcol[ni] = bias[pn * 128 + ni * 16 + cl];

    float keep[8][4];
    #pragma unroll
    for (int r = 0; r < 4; ++r) {
        float s = 0.f;
        #pragma unroll
        for (int ni = 0; ni < 8; ++ni) {
            float v = fmaxf(acc[ni][r] + bcol[ni], 0.f);
            keep[ni][r] = v;
            s += v * v;
        }
        #pragma unroll
        for (int m = 1; m < 16; m <<= 1) s += __shfl_xor(s, m, 64);
        if (cl == 0) ssq_s[rt][pn][g * 4 + r] = s;
    }
    __syncthreads();
    #pragma unroll
    for (int r = 0; r < 4; ++r) {
        const int rl = g * 4 + r;
        const float tot = ssq_s[rt][0][rl] + ssq_s[rt][1][rl];
        const float rn = tot > 0.f ? rsqrtf(tot) : 1.0f;
        const int row = m0 + rl;
        if (row < M) {
            #pragma unroll
            for (int ni = 0; ni < 8; ++ni)
                Cf[(size_t)row * 256 + pn * 128 + ni * 16 + cl] = keep[ni][r] * rn;
        }
    }
}

// ---- per-dst aggregation: one wave per dst; unroll-2 on edges
__global__ __launch_bounds__(256) void aggregate_kernel(
    const unsigned short* __restrict__ nft, const float* __restrict__ h_dst,
    const float* __restrict__ weights, const int* __restrict__ src_idx,
    const int* __restrict__ edge_list, const int* __restrict__ offsets,
    unsigned short* __restrict__ xb)
{
    int d = blockIdx.x * 4 + (threadIdx.x >> 6);
    if (d >= N_DST) return;
    int lane = threadIdx.x & 63;
    int p0 = offsets[d], p1 = offsets[d + 1];
    float a0 = 0.f, a1 = 0.f, a2 = 0.f, a3 = 0.f, wsum = 0.f;
    int p = p0;
    for (; p + 1 < p1; p += 2) {
        int e0 = edge_list[p], e1 = edge_list[p + 1];
        float w0 = weights[e0], w1 = weights[e1];
        int s0 = src_idx[e0], s1 = src_idx[e1];
        uint2 v0 = *reinterpret_cast<const uint2*>(nft + (size_t)s0 * 256 + lane * 4);
        uint2 v1 = *reinterpret_cast<const uint2*>(nft + (size_t)s1 * 256 + lane * 4);
        wsum += w0 + w1;
        a0 += w0 * bf2f(v0.x & 0xffffu) + w1 * bf2f(v1.x & 0xffffu);
        a1 += w0 * bf2f(v0.x >> 16)     + w1 * bf2f(v1.x >> 16);
        a2 += w0 * bf2f(v0.y & 0xffffu) + w1 * bf2f(v1.y & 0xffffu);
        a3 += w0 * bf2f(v0.y >> 16)     + w1 * bf2f(v1.y >> 16);
    }
    if (p < p1) {
        int e = edge_list[p];
        float w = weights[e];
        int s = src_idx[e];
        wsum += w;
        uint2 v = *reinterpret_cast<const uint2*>(nft + (size_t)s * 256 + lane * 4);
        a0 += w * bf2f(v.x & 0xffffu);
        a1 += w * bf2f(v.x >> 16);
        a2 += w * bf2f(v.y & 0xffffu);
        a3 += w * bf2f(v.y >> 16);
    }
    float inv = 1.0f / fmaxf(wsum, 1.0f);
    uint2 pk;
    pk.x = (unsigned)f2bf(a0 * inv) | ((unsigned)f2bf(a1 * inv) << 16);
    pk.y = (unsigned)f2bf(a2 * inv) | ((unsigned)f2bf(a3 * inv) << 16);
    *reinterpret_cast<uint2*>(xb + (size_t)d * 512 + lane * 4) = pk;
    float4 h = *reinterpret_cast<const float4*>(h_dst + (size_t)d * 256 + lane * 4);
    uint2 q;
    q.x = (unsigned)f2bf(h.x) | ((unsigned)f2bf(h.y) << 16);
    q.y = (unsigned)f2bf(h.z) | ((unsigned)f2bf(h.w) << 16);
    *reinterpret_cast<uint2*>(xb + (size_t)d * 512 + 256 + lane * 4) = q;
}

extern "C" void kernel_launch(void* const* d_in, const int* in_sizes, int n_in,
                              void* d_out, int out_size, void* d_ws, size_t ws_size,
                              hipStream_t stream) {
    const float* h_src   = (const float*)d_in[0];
    const float* h_dst   = (const float*)d_in[1];
    const float* weights = (const float*)d_in[2];
    const float* Q_w     = (const float*)d_in[3];
    const float* Q_b     = (const float*)d_in[4];
    const float* W_w     = (const float*)d_in[5];
    const float* W_b     = (const float*)d_in[6];
    const int* src_idx   = (const int*)d_in[7];
    const int* dst_idx   = (const int*)d_in[8];
    float* out = (float*)d_out;

    char* ws = (char*)d_ws;
    unsigned short* nft = (unsigned short*)(ws);               // 51,200,000
    unsigned short* xb  = (unsigned short*)(ws + 51200000);    // 25,600,000
    unsigned short* Qt  = (unsigned short*)(ws + 76800000);    // 131,072
    unsigned short* Wt  = (unsigned short*)(ws + 76931072);    // 262,144
    int* counts    = (int*)(ws + 77193216);                    // 100,000
    int* offsets   = (int*)(ws + 77293216);                    // 100,004
    int* edge_list = (int*)(ws + 77393220);                    // 1,200,000 (~78.6 MB)

    hipMemsetAsync(counts, 0, N_DST * sizeof(int), stream);

    cast_weights<<<768, 256, 0, stream>>>(Q_w, W_w, Qt, Wt);
    hist_kernel<<<(N_EDGE + 255) / 256, 256, 0, stream>>>(dst_idx, counts);
    scan_kernel<<<1, 1024, 0, stream>>>(counts, offsets, N_DST);
    scatter_kernel<<<(N_EDGE + 255) / 256, 256, 0, stream>>>(dst_idx, offsets, counts, edge_list);

    // 256 blocks (1/CU), balanced tile ranges; B->LDS once per block
    gemm1_lds<<<256, 768, 0, stream>>>(h_src, Qt, Q_b, nft);

    aggregate_kernel<<<N_DST / 4, 256, 0, stream>>>(
        nft, h_dst, weights, src_idx, edge_list, offsets, xb);

    // 782 blocks x 4 waves (2 row-tiles x 2 col panels)
    gemm2_l2<<<782, 256, 0, stream>>>(xb, Wt, W_b, out, N_DST);

    (void)in_sizes; (void)n_in; (void)out_size; (void)ws_size;
}

// Round 8
// 191.226 us; speedup vs baseline: 1.4052x; 1.2946x over previous
//
#include <hip/hip_runtime.h>
#include <hip/hip_bf16.h>
#include <cstdint>

#define N_SRC 100000
#define N_DST 25000
#define N_EDGE 300000
// D_IN = D_HID = D_OUT = 256, concat K = 512

typedef float f32x4 __attribute__((ext_vector_type(4)));
typedef __bf16 bf16x8 __attribute__((ext_vector_type(8)));

typedef const __attribute__((address_space(1))) void gv_t;
typedef __attribute__((address_space(3))) void lv_t;

__device__ __forceinline__ unsigned short f2bf(float f) {
    union { float f; unsigned int u; } v; v.f = f;
    unsigned int u = v.u;
    u += 0x7FFFu + ((u >> 16) & 1u);   // RNE; inputs finite
    return (unsigned short)(u >> 16);
}
__device__ __forceinline__ float bf2f(unsigned int bits16) {
    union { unsigned int u; float f; } v; v.u = bits16 << 16;
    return v.f;
}

// ---- cast + transpose weights: Qt[n][k] = bf16(Q_w[k][n]), Wt[n][k] = bf16(W_w[k][n])
__global__ void cast_weights(const float* __restrict__ Qw, const float* __restrict__ Ww,
                             unsigned short* __restrict__ Qt, unsigned short* __restrict__ Wt) {
    int i = blockIdx.x * blockDim.x + threadIdx.x;
    if (i < 256 * 256) {
        int n = i >> 8, k = i & 255;
        Qt[n * 256 + k] = f2bf(Qw[k * 256 + n]);
    } else if (i < 256 * 256 + 512 * 256) {
        int j = i - 256 * 256;
        int n = j >> 9, k = j & 511;
        Wt[n * 512 + k] = f2bf(Ww[k * 256 + n]);
    }
}

// ---- CSR build
__global__ void hist_kernel(const int* __restrict__ dst_idx, int* __restrict__ counts) {
    int i = blockIdx.x * blockDim.x + threadIdx.x;
    if (i < N_EDGE) atomicAdd(&counts[dst_idx[i]], 1);
}

__global__ __launch_bounds__(1024) void scan_kernel(const int* __restrict__ counts,
                                                    int* __restrict__ offsets, int n) {
    __shared__ int wsum[16];
    const int t = threadIdx.x;
    const int wid = t >> 6, lane = t & 63;
    int carry = 0;
    if (t == 0) offsets[0] = 0;
    for (int base = 0; base < n; base += 1024) {
        int x = (base + t < n) ? counts[base + t] : 0;
        #pragma unroll
        for (int off = 1; off < 64; off <<= 1) {
            int y = __shfl_up(x, off, 64);
            if (lane >= off) x += y;
        }
        if (lane == 63) wsum[wid] = x;
        __syncthreads();
        if (t < 16) {
            int w = wsum[t];
            #pragma unroll
            for (int off = 1; off < 16; off <<= 1) {
                int y = __shfl_up(w, off, 64);
                if (t >= off) w += y;
            }
            wsum[t] = w;
        }
        __syncthreads();
        int pre = (wid > 0) ? wsum[wid - 1] : 0;
        int incl = carry + pre + x;
        if (base + t < n) offsets[base + t + 1] = incl;
        carry += wsum[15];
        __syncthreads();
    }
}

__global__ void scatter_kernel(const int* __restrict__ dst_idx, const int* __restrict__ offsets,
                               int* __restrict__ counts, int* __restrict__ edge_list) {
    int i = blockIdx.x * blockDim.x + threadIdx.x;
    if (i < N_EDGE) {
        int d = dst_idx[i];
        int pos = offsets[d] + (atomicSub(&counts[d], 1) - 1);
        edge_list[pos] = i;
    }
}

// ---- GEMM1 (m97 structure): nft = relu(h_src @ Qt^T + Qb), bf16 out.
// Block 64(M)x256(N), 4 waves x 64x64. A (f32) double-buffered in LDS via
// global_load_lds w16, source pre-XOR-swizzled per 16B granule (rule #21);
// ds_read_b128 with matching XOR -> conflict-free. B direct global->reg from
// L2 per k-tile. One __syncthreads per k-tile; compiler schedules the rest.
__global__ __launch_bounds__(256) void gemm1_97(
    const float* __restrict__ Af, const unsigned short* __restrict__ Bt,
    const float* __restrict__ bias, unsigned short* __restrict__ Cb)
{
    __shared__ __align__(16) float Asf[2][64 * 64];   // 16KB x 2
    const int tid = threadIdx.x;
    const int wv = tid >> 6, lane = tid & 63, g = lane >> 4, cl = lane & 15;
    const int m0 = blockIdx.x * 64;
    const int n0 = wv * 64;
    const int srow = tid >> 4, sblk = tid & 15;

    f32x4 acc[4][4];
    #pragma unroll
    for (int i = 0; i < 4; ++i)
        #pragma unroll
        for (int j = 0; j < 4; ++j)
            acc[i][j] = (f32x4){0.f, 0.f, 0.f, 0.f};

    auto stage = [&](int buf, int kt) {
        #pragma unroll
        for (int i = 0; i < 4; ++i) {
            const int row = i * 16 + srow;
            const int grow = min(m0 + row, N_SRC - 1);
            const float* gp = Af + (size_t)grow * 256 + kt * 64 + ((sblk ^ (row & 7)) << 2);
            __builtin_amdgcn_global_load_lds(
                (gv_t*)gp,
                (lv_t*)((char*)&Asf[buf][0] + i * 4096 + wv * 1024), 16, 0, 0);
        }
    };

    stage(0, 0);
    __syncthreads();

    #pragma unroll
    for (int kt = 0; kt < 4; ++kt) {
        const int buf = kt & 1;
        if (kt < 3) stage(buf ^ 1, kt + 1);

        uint4 bfrag[2][4];
        #pragma unroll
        for (int ks = 0; ks < 2; ++ks)
            #pragma unroll
            for (int ni = 0; ni < 4; ++ni)
                bfrag[ks][ni] = *reinterpret_cast<const uint4*>(
                    Bt + (size_t)(n0 + ni * 16 + cl) * 256 + kt * 64 + ks * 32 + g * 8);

        #pragma unroll
        for (int ks = 0; ks < 2; ++ks) {
            #pragma unroll
            for (int mi = 0; mi < 4; ++mi) {
                const int row = mi * 16 + cl;
                const f32x4 lo = *reinterpret_cast<const f32x4*>(
                    (const char*)&Asf[buf][0] + row * 256 + (((ks * 8 + g * 2 + 0) ^ (cl & 7)) << 4));
                const f32x4 hi = *reinterpret_cast<const f32x4*>(
                    (const char*)&Asf[buf][0] + row * 256 + (((ks * 8 + g * 2 + 1) ^ (cl & 7)) << 4));
                bf16x8 af;
                af[0] = (__bf16)lo[0]; af[1] = (__bf16)lo[1]; af[2] = (__bf16)lo[2]; af[3] = (__bf16)lo[3];
                af[4] = (__bf16)hi[0]; af[5] = (__bf16)hi[1]; af[6] = (__bf16)hi[2]; af[7] = (__bf16)hi[3];
                #pragma unroll
                for (int ni = 0; ni < 4; ++ni)
                    acc[mi][ni] = __builtin_amdgcn_mfma_f32_16x16x32_bf16(
                        af, __builtin_bit_cast(bf16x8, bfrag[ks][ni]), acc[mi][ni], 0, 0, 0);
            }
        }
        __syncthreads();
    }

    float bcol[4];
    #pragma unroll
    for (int ni = 0; ni < 4; ++ni) bcol[ni] = bias[n0 + ni * 16 + cl];
    #pragma unroll
    for (int mi = 0; mi < 4; ++mi) {
        const int rowb = m0 + mi * 16 + g * 4;
        #pragma unroll
        for (int ni = 0; ni < 4; ++ni) {
            const int col = n0 + ni * 16 + cl;
            #pragma unroll
            for (int r = 0; r < 4; ++r) {
                const int row = rowb + r;
                if (row < N_SRC) {
                    float v = fmaxf(acc[mi][ni][r] + bcol[ni], 0.f);
                    Cb[(size_t)row * 256 + col] = f2bf(v);
                }
            }
        }
    }
}

// ---- GEMM2 (m97 structure): out = rownorm(relu(xb @ Wt^T + Wb)), f32 out.
// Same shape; A is bf16 (8KB/buf). Row-norm: the 4 waves each own a 64-col
// panel of the SAME 64 rows -> norml[4][64] exchange, one extra barrier.
__global__ __launch_bounds__(256) void gemm2_97(
    const unsigned short* __restrict__ Ab, const unsigned short* __restrict__ Bt,
    const float* __restrict__ bias, float* __restrict__ Cf, int M)
{
    __shared__ __align__(16) unsigned short Ash[2][64 * 64];  // 8KB x 2
    __shared__ float norml[4][64];
    const int tid = threadIdx.x;
    const int wv = tid >> 6, lane = tid & 63, g = lane >> 4, cl = lane & 15;
    const int m0 = blockIdx.x * 64;
    const int n0 = wv * 64;
    const int srow = tid >> 3, sblk = tid & 7;

    f32x4 acc[4][4];
    #pragma unroll
    for (int i = 0; i < 4; ++i)
        #pragma unroll
        for (int j = 0; j < 4; ++j)
            acc[i][j] = (f32x4){0.f, 0.f, 0.f, 0.f};

    auto stage = [&](int buf, int kt) {
        #pragma unroll
        for (int i = 0; i < 2; ++i) {
            const int row = i * 32 + srow;
            const int grow = min(m0 + row, M - 1);
            const unsigned short* gp = Ab + (size_t)grow * 512 + kt * 64 + ((sblk ^ (row & 7)) << 3);
            __builtin_amdgcn_global_load_lds(
                (gv_t*)gp,
                (lv_t*)((char*)&Ash[buf][0] + i * 4096 + wv * 1024), 16, 0, 0);
        }
    };

    stage(0, 0);
    __syncthreads();

    #pragma unroll
    for (int kt = 0; kt < 8; ++kt) {
        const int buf = kt & 1;
        if (kt < 7) stage(buf ^ 1, kt + 1);

        uint4 bfrag[2][4];
        #pragma unroll
        for (int ks = 0; ks < 2; ++ks)
            #pragma unroll
            for (int ni = 0; ni < 4; ++ni)
                bfrag[ks][ni] = *reinterpret_cast<const uint4*>(
                    Bt + (size_t)(n0 + ni * 16 + cl) * 512 + kt * 64 + ks * 32 + g * 8);

        #pragma unroll
        for (int ks = 0; ks < 2; ++ks) {
            #pragma unroll
            for (int mi = 0; mi < 4; ++mi) {
                const int row = mi * 16 + cl;
                const bf16x8 af = *reinterpret_cast<const bf16x8*>(
                    (const char*)&Ash[buf][0] + row * 128 + (((ks * 4 + g) ^ (cl & 7)) << 4));
                #pragma unroll
                for (int ni = 0; ni < 4; ++ni)
                    acc[mi][ni] = __builtin_amdgcn_mfma_f32_16x16x32_bf16(
                        af, __builtin_bit_cast(bf16x8, bfrag[ks][ni]), acc[mi][ni], 0, 0, 0);
            }
        }
        __syncthreads();
    }

    float bcol[4];
    #pragma unroll
    for (int ni = 0; ni < 4; ++ni) bcol[ni] = bias[n0 + ni * 16 + cl];

    #pragma unroll
    for (int mi = 0; mi < 4; ++mi) {
        #pragma unroll
        for (int r = 0; r < 4; ++r) {
            float s = 0.f;
            #pragma unroll
            for (int ni = 0; ni < 4; ++ni) {
                float v = fmaxf(acc[mi][ni][r] + bcol[ni], 0.f);
                acc[mi][ni][r] = v;
                s += v * v;
            }
            #pragma unroll
            for (int m = 1; m < 16; m <<= 1) s += __shfl_xor(s, m, 64);
            if (cl == 0) norml[wv][mi * 16 + g * 4 + r] = s;
        }
    }
    __syncthreads();
    #pragma unroll
    for (int mi = 0; mi < 4; ++mi) {
        #pragma unroll
        for (int r = 0; r < 4; ++r) {
            const int rl = mi * 16 + g * 4 + r;
            const float tot = norml[0][rl] + norml[1][rl] + norml[2][rl] + norml[3][rl];
            const float rn = tot > 0.f ? rsqrtf(tot) : 1.0f;
            const int row = m0 + rl;
            if (row < M) {
                #pragma unroll
                for (int ni = 0; ni < 4; ++ni)
                    Cf[(size_t)row * 256 + n0 + ni * 16 + cl] = acc[mi][ni][r] * rn;
            }
        }
    }
}

// ---- per-dst aggregation: one wave per dst; unroll-2 on edges
__global__ __launch_bounds__(256) void aggregate_kernel(
    const unsigned short* __restrict__ nft, const float* __restrict__ h_dst,
    const float* __restrict__ weights, const int* __restrict__ src_idx,
    const int* __restrict__ edge_list, const int* __restrict__ offsets,
    unsigned short* __restrict__ xb)
{
    int d = blockIdx.x * 4 + (threadIdx.x >> 6);
    if (d >= N_DST) return;
    int lane = threadIdx.x & 63;
    int p0 = offsets[d], p1 = offsets[d + 1];
    float a0 = 0.f, a1 = 0.f, a2 = 0.f, a3 = 0.f, wsum = 0.f;
    int p = p0;
    for (; p + 1 < p1; p += 2) {
        int e0 = edge_list[p], e1 = edge_list[p + 1];
        float w0 = weights[e0], w1 = weights[e1];
        int s0 = src_idx[e0], s1 = src_idx[e1];
        uint2 v0 = *reinterpret_cast<const uint2*>(nft + (size_t)s0 * 256 + lane * 4);
        uint2 v1 = *reinterpret_cast<const uint2*>(nft + (size_t)s1 * 256 + lane * 4);
        wsum += w0 + w1;
        a0 += w0 * bf2f(v0.x & 0xffffu) + w1 * bf2f(v1.x & 0xffffu);
        a1 += w0 * bf2f(v0.x >> 16)     + w1 * bf2f(v1.x >> 16);
        a2 += w0 * bf2f(v0.y & 0xffffu) + w1 * bf2f(v1.y & 0xffffu);
        a3 += w0 * bf2f(v0.y >> 16)     + w1 * bf2f(v1.y >> 16);
    }
    if (p < p1) {
        int e = edge_list[p];
        float w = weights[e];
        int s = src_idx[e];
        wsum += w;
        uint2 v = *reinterpret_cast<const uint2*>(nft + (size_t)s * 256 + lane * 4);
        a0 += w * bf2f(v.x & 0xffffu);
        a1 += w * bf2f(v.x >> 16);
        a2 += w * bf2f(v.y & 0xffffu);
        a3 += w * bf2f(v.y >> 16);
    }
    float inv = 1.0f / fmaxf(wsum, 1.0f);
    uint2 pk;
    pk.x = (unsigned)f2bf(a0 * inv) | ((unsigned)f2bf(a1 * inv) << 16);
    pk.y = (unsigned)f2bf(a2 * inv) | ((unsigned)f2bf(a3 * inv) << 16);
    *reinterpret_cast<uint2*>(xb + (size_t)d * 512 + lane * 4) = pk;
    float4 h = *reinterpret_cast<const float4*>(h_dst + (size_t)d * 256 + lane * 4);
    uint2 q;
    q.x = (unsigned)f2bf(h.x) | ((unsigned)f2bf(h.y) << 16);
    q.y = (unsigned)f2bf(h.z) | ((unsigned)f2bf(h.w) << 16);
    *reinterpret_cast<uint2*>(xb + (size_t)d * 512 + 256 + lane * 4) = q;
}

extern "C" void kernel_launch(void* const* d_in, const int* in_sizes, int n_in,
                              void* d_out, int out_size, void* d_ws, size_t ws_size,
                              hipStream_t stream) {
    const float* h_src   = (const float*)d_in[0];
    const float* h_dst   = (const float*)d_in[1];
    const float* weights = (const float*)d_in[2];
    const float* Q_w     = (const float*)d_in[3];
    const float* Q_b     = (const float*)d_in[4];
    const float* W_w     = (const float*)d_in[5];
    const float* W_b     = (const float*)d_in[6];
    const int* src_idx   = (const int*)d_in[7];
    const int* dst_idx   = (const int*)d_in[8];
    float* out = (float*)d_out;

    char* ws = (char*)d_ws;
    unsigned short* nft = (unsigned short*)(ws);               // 51,200,000
    unsigned short* xb  = (unsigned short*)(ws + 51200000);    // 25,600,000
    unsigned short* Qt  = (unsigned short*)(ws + 76800000);    // 131,072
    unsigned short* Wt  = (unsigned short*)(ws + 76931072);    // 262,144
    int* counts    = (int*)(ws + 77193216);                    // 100,000
    int* offsets   = (int*)(ws + 77293216);                    // 100,004
    int* edge_list = (int*)(ws + 77393220);                    // 1,200,000 (~78.6 MB)

    hipMemsetAsync(counts, 0, N_DST * sizeof(int), stream);

    cast_weights<<<768, 256, 0, stream>>>(Q_w, W_w, Qt, Wt);
    hist_kernel<<<(N_EDGE + 255) / 256, 256, 0, stream>>>(dst_idx, counts);
    scan_kernel<<<1, 1024, 0, stream>>>(counts, offsets, N_DST);
    scatter_kernel<<<(N_EDGE + 255) / 256, 256, 0, stream>>>(dst_idx, offsets, counts, edge_list);

    gemm1_97<<<(N_SRC + 63) / 64, 256, 0, stream>>>(h_src, Qt, Q_b, nft);

    aggregate_kernel<<<N_DST / 4, 256, 0, stream>>>(
        nft, h_dst, weights, src_idx, edge_list, offsets, xb);

    gemm2_97<<<(N_DST + 63) / 64, 256, 0, stream>>>(xb, Wt, W_b, out, N_DST);

    (void)in_sizes; (void)n_in; (void)out_size; (void)ws_size;
}